// Round 10
// baseline (394.588 us; speedup 1.0000x reference)
//
#include <hip/hip_runtime.h>
#include <math.h>

#define NN 20480
#define NE 327680
#define NBATCH 16

typedef float v2f __attribute__((ext_vector_type(2)));

static __device__ __forceinline__ v2f vmax0(v2f a) {
  v2f r; r.x = fmaxf(a.x, 0.f); r.y = fmaxf(a.y, 0.f); return r;
}
#define VMAX0 vmax0

// ---------------- prep: histogram (1280 blk) + embT4 transpose (72 blk) -----
__global__ __launch_bounds__(256) void prep_kernel(
    const int* __restrict__ dst, int* __restrict__ cnt,
    const float* __restrict__ e4, float* __restrict__ t4) {
  int b = blockIdx.x;
  if (b < NE / 256) {
    int e = b * 256 + threadIdx.x;
    atomicAdd(&cnt[dst[e]], 1);
  } else {
    int idx = (b - NE / 256) * 256 + threadIdx.x;   // 0 .. 18431
    int t = idx >> 9, r = idx & 511, o = r >> 3, i = r & 7;
    t4[idx] = e4[(t << 9) + i * 64 + o];            // [t][i][o] -> [t][o][i]
  }
}

// ------- exclusive scan (1 block); writes off AND cur; zeroes pool ----------
__global__ __launch_bounds__(1024) void scan_kernel(const int* __restrict__ cnt,
                                                    int* __restrict__ off,
                                                    int* __restrict__ cur,
                                                    float* __restrict__ poolz) {
  __shared__ int part[1024];
  int tid = threadIdx.x;
  if (tid < NBATCH * 64 + NBATCH) poolz[tid] = 0.f;
  const int PT = NN / 1024;              // 20 per thread
  int loc[PT];
  int run = 0;
  int base = tid * PT;
#pragma unroll
  for (int k = 0; k < PT; k++) { loc[k] = run; run += cnt[base + k]; }
  part[tid] = run;
  __syncthreads();
  for (int d = 1; d < 1024; d <<= 1) {
    int t = (tid >= d) ? part[tid - d] : 0;
    __syncthreads();
    part[tid] += t;
    __syncthreads();
  }
  int pre = (tid == 0) ? 0 : part[tid - 1];
#pragma unroll
  for (int k = 0; k < PT; k++) {
    off[base + k] = pre + loc[k];
    cur[base + k] = pre + loc[k];
  }
  if (tid == 1023) off[NN] = pre + run;  // == NE
}

__global__ void scatter_kernel(const int* __restrict__ src, const int* __restrict__ dst,
                               const int* __restrict__ etype, const float* __restrict__ eattr,
                               int* __restrict__ cur, float4* __restrict__ es) {
  int e = blockIdx.x * blockDim.x + threadIdx.x;
  if (e >= NE) return;
  int d = dst[e];
  int pos = atomicAdd(&cur[d], 1);
  es[pos] = make_float4(__int_as_float(src[e]), __int_as_float(etype[e]),
                        eattr[2 * e], eattr[2 * e + 1]);
}

// ---------------- fused layer 1 (cin=16, cout=8) — unchanged (R9) -----------
__global__ __launch_bounds__(256) void layer_small16(
    const int* __restrict__ off, const float4* __restrict__ es,
    const float* __restrict__ h_in,
    const float* __restrict__ emb, const float* __restrict__ wh,
    const float* __restrict__ bh, const float* __restrict__ wg,
    const float* __restrict__ bg,
    const float* __restrict__ root, const float* __restrict__ bias,
    float* __restrict__ h_out) {
  constexpr int D = 128;
  constexpr int S = D + 1;               // odd stride spreads banks
  __shared__ float semb[36 * S];
  for (int idx = threadIdx.x; idx < 36 * D; idx += 256) {
    int t = idx / D, io = idx - t * D;
    semb[t * S + io] = emb[idx];
  }
  int lane = threadIdx.x & 63;
  int o = lane & 7;
  int ihalf = (lane >> 3) & 1;
  int esub = lane >> 4;                  // 0..3
  int ibase = ihalf * 8;
  v2f rwh0[4], rwh1[4], rbh[4], rwg0[4], rwg1[4], rbg[4], rroot[4];
#pragma unroll
  for (int p = 0; p < 4; p++) {
    int a = (ibase + 2 * p) * 8 + o, b = (ibase + 2 * p + 1) * 8 + o;
    rwh0[p] = (v2f){wh[a], wh[b]};
    rwh1[p] = (v2f){wh[D + a], wh[D + b]};
    rbh[p]  = (v2f){bh[a], bh[b]};
    rwg0[p] = (v2f){wg[a], wg[b]};
    rwg1[p] = (v2f){wg[D + a], wg[D + b]};
    rbg[p]  = (v2f){bg[a], bg[b]};
    rroot[p] = (v2f){root[a], root[b]};
  }
  float rbias = bias[o];
  __syncthreads();
  int wid = __builtin_amdgcn_readfirstlane(blockIdx.x * 4 + (threadIdx.x >> 6));
  for (int k = 0; k < 2; k++) {
    int n = wid * 2 + k;
    int beg = off[n], end = off[n + 1];
    float acc = 0.f;
    for (int j = beg + esub; j < end; j += 4) {
      float4 rec = es[j];
      int s = __float_as_int(rec.x);
      int t = __float_as_int(rec.y);
      v2f ef0 = (v2f){rec.z, rec.z}, ef1 = (v2f){rec.w, rec.w};
      const float4* hp = (const float4*)(h_in + s * 16 + ibase);
      float4 h0 = hp[0], h1 = hp[1];
      v2f hv[4] = {(v2f){h0.x, h0.y}, (v2f){h0.z, h0.w},
                   (v2f){h1.x, h1.y}, (v2f){h1.z, h1.w}};
      const float* st = &semb[t * S + ibase * 8 + o];
      v2f msg = {0.f, 0.f};
#pragma unroll
      for (int p = 0; p < 4; p++) {
        v2f hval = ef0 * rwh0[p] + ef1 * rwh1[p] + rbh[p];
        v2f gval = ef0 * rwg0[p] + ef1 * rwg1[p] + rbg[p];
        v2f stv = (v2f){st[(2 * p) * 8], st[(2 * p + 1) * 8]};
        msg += hv[p] * VMAX0(stv * hval + gval);
      }
      acc += msg.x + msg.y;
    }
    acc += __shfl_xor(acc, 8);
    acc += __shfl_xor(acc, 16);
    acc += __shfl_xor(acc, 32);
    const float* hn = h_in + n * 16 + ibase;
    v2f rtv = {0.f, 0.f};
#pragma unroll
    for (int p = 0; p < 4; p++)
      rtv += (v2f){hn[2 * p], hn[2 * p + 1]} * rroot[p];
    float rt = rtv.x + rtv.y;
    rt += __shfl_xor(rt, 8);
    float deg = (float)(end - beg);
    float val = fmaxf(rbias + rt + acc / fmaxf(deg, 1.f), 0.f);
    if (lane < 8) h_out[n * 8 + o] = val;
  }
}

// ---------------- fused layer, cin=8 cout=8 (L2,L3) — unchanged (R9) --------
__global__ __launch_bounds__(256) void layer_small8(
    const int* __restrict__ off, const float4* __restrict__ es,
    const float* __restrict__ h_in,
    const float* __restrict__ emb, const float* __restrict__ wh,
    const float* __restrict__ bh, const float* __restrict__ wg,
    const float* __restrict__ bg,
    const float* __restrict__ root, const float* __restrict__ bias,
    float* __restrict__ h_out) {
  constexpr int D = 64;
  constexpr int S = D + 1;
  __shared__ float semb[36 * S];
  for (int idx = threadIdx.x; idx < 36 * D; idx += 256) {
    int t = idx / D, io = idx - t * D;
    semb[t * S + io] = emb[idx];
  }
  int lane = threadIdx.x & 63;
  int o = lane & 7, esub = lane >> 3;
  v2f rwh0[4], rwh1[4], rbh[4], rwg0[4], rwg1[4], rbg[4], rroot[4];
#pragma unroll
  for (int p = 0; p < 4; p++) {
    int a = (2 * p) * 8 + o, b = (2 * p + 1) * 8 + o;
    rwh0[p] = (v2f){wh[a], wh[b]};
    rwh1[p] = (v2f){wh[D + a], wh[D + b]};
    rbh[p]  = (v2f){bh[a], bh[b]};
    rwg0[p] = (v2f){wg[a], wg[b]};
    rwg1[p] = (v2f){wg[D + a], wg[D + b]};
    rbg[p]  = (v2f){bg[a], bg[b]};
    rroot[p] = (v2f){root[a], root[b]};
  }
  float rbias = bias[o];
  __syncthreads();
  int wid = __builtin_amdgcn_readfirstlane(blockIdx.x * 4 + (threadIdx.x >> 6));
  for (int k = 0; k < 4; k++) {
    int n = wid * 4 + k;
    int beg = off[n], end = off[n + 1];
    float acc = 0.f;
    for (int j = beg + esub; j < end; j += 8) {
      float4 rec = es[j];
      int s = __float_as_int(rec.x);
      int t = __float_as_int(rec.y);
      v2f ef0 = (v2f){rec.z, rec.z}, ef1 = (v2f){rec.w, rec.w};
      const float4* hp = (const float4*)(h_in + s * 8);
      float4 h0 = hp[0], h1 = hp[1];
      v2f hv[4] = {(v2f){h0.x, h0.y}, (v2f){h0.z, h0.w},
                   (v2f){h1.x, h1.y}, (v2f){h1.z, h1.w}};
      const float* st = &semb[t * S + o];
      v2f msg = {0.f, 0.f};
#pragma unroll
      for (int p = 0; p < 4; p++) {
        v2f hval = ef0 * rwh0[p] + ef1 * rwh1[p] + rbh[p];
        v2f gval = ef0 * rwg0[p] + ef1 * rwg1[p] + rbg[p];
        v2f stv = (v2f){st[(2 * p) * 8], st[(2 * p + 1) * 8]};
        msg += hv[p] * VMAX0(stv * hval + gval);
      }
      acc += msg.x + msg.y;
    }
    acc += __shfl_xor(acc, 8);
    acc += __shfl_xor(acc, 16);
    acc += __shfl_xor(acc, 32);
    float deg = (float)(end - beg);
    const float* hn = h_in + n * 8;
    v2f rtv = {0.f, 0.f};
#pragma unroll
    for (int p = 0; p < 4; p++)
      rtv += (v2f){hn[2 * p], hn[2 * p + 1]} * rroot[p];
    float val = fmaxf(rbias + rtv.x + rtv.y + acc / fmaxf(deg, 1.f), 0.f);
    if (lane < 8) h_out[n * 8 + o] = val;
  }
}

// ---------------- fused layer 4 + gated pooling (cin=8, cout=64) ------------
// One node per wave, lane = out channel. s_load path (R9) + DEPTH-2 SOFTWARE
// PIPELINE: recs fetched 2 pairs ahead, operands (h rows, emb rows) 1 pair
// ahead — both dependent round trips overlap compute. Epilogue does the gated
// pooling atomics directly (no h4 materialization, pool1 dispatch removed).
__global__ __launch_bounds__(256) void layer_l4p(
    const int* __restrict__ off, const float4* __restrict__ es,
    const float* __restrict__ h_in, const float* __restrict__ embT,
    const float* __restrict__ wh, const float* __restrict__ bh,
    const float* __restrict__ wg, const float* __restrict__ bg,
    const float* __restrict__ root, const float* __restrict__ bias,
    const int* __restrict__ ct,
    float* __restrict__ pooled, float* __restrict__ pcnt) {
  int lane = threadIdx.x & 63;
  v2f rwh0[4], rwh1[4], rbh[4], rwg0[4], rwg1[4], rbg[4];
#pragma unroll
  for (int p = 0; p < 4; p++) {
    int a = (2 * p) * 64 + lane, b = (2 * p + 1) * 64 + lane;
    rwh0[p] = (v2f){wh[a], wh[b]};
    rwh1[p] = (v2f){wh[512 + a], wh[512 + b]};
    rbh[p]  = (v2f){bh[a], bh[b]};
    rwg0[p] = (v2f){wg[a], wg[b]};
    rwg1[p] = (v2f){wg[512 + a], wg[512 + b]};
    rbg[p]  = (v2f){bg[a], bg[b]};
  }
  int n = __builtin_amdgcn_readfirstlane((int)(blockIdx.x * 4) + (int)(threadIdx.x >> 6));
  int beg = off[n], end = off[n + 1];
  int degi = end - beg;
  int npair = degi >> 1;
  float acc0 = 0.f, acc1 = 0.f;

  // pipeline state: recs for current (A) and next (B) pair; operands for A
  float4 rA0, rA1, rB0, rB1;
  float4 hA00, hA01, hA10, hA11, sA00, sA01, sA10, sA11;
  if (npair > 0) { rA0 = es[beg]; rA1 = es[beg + 1]; }
  if (npair > 1) { rB0 = es[beg + 2]; rB1 = es[beg + 3]; }
  if (npair > 0) {
    int s0 = __float_as_int(rA0.x), t0 = __float_as_int(rA0.y);
    int s1 = __float_as_int(rA1.x), t1 = __float_as_int(rA1.y);
    const float4* hp0 = (const float4*)(h_in + s0 * 8);
    const float4* hp1 = (const float4*)(h_in + s1 * 8);
    const float4* ep0 = (const float4*)(embT + t0 * 512 + lane * 8);
    const float4* ep1 = (const float4*)(embT + t1 * 512 + lane * 8);
    hA00 = hp0[0]; hA01 = hp0[1]; hA10 = hp1[0]; hA11 = hp1[1];
    sA00 = ep0[0]; sA01 = ep0[1]; sA10 = ep1[0]; sA11 = ep1[1];
  }
#pragma unroll 2
  for (int it = 0; it < npair; ++it) {
    // prefetch recs for pair it+2 (address clamped to a safe in-range slot)
    int eC = beg + 2 * it + 4;
    int eCc = (eC + 1 < end) ? eC : beg;
    float4 rC0 = es[eCc], rC1 = es[eCc + 1];
    // load operands for next pair (rB already arrived)
    float4 hB00, hB01, hB10, hB11, sB00, sB01, sB10, sB11;
    if (it + 1 < npair) {
      int s0 = __float_as_int(rB0.x), t0 = __float_as_int(rB0.y);
      int s1 = __float_as_int(rB1.x), t1 = __float_as_int(rB1.y);
      const float4* hp0 = (const float4*)(h_in + s0 * 8);
      const float4* hp1 = (const float4*)(h_in + s1 * 8);
      const float4* ep0 = (const float4*)(embT + t0 * 512 + lane * 8);
      const float4* ep1 = (const float4*)(embT + t1 * 512 + lane * 8);
      hB00 = hp0[0]; hB01 = hp0[1]; hB10 = hp1[0]; hB11 = hp1[1];
      sB00 = ep0[0]; sB01 = ep0[1]; sB10 = ep1[0]; sB11 = ep1[1];
    }
    // compute current pair (operands already in flight/arrived)
    {
      v2f sv0[4] = {(v2f){sA00.x, sA00.y}, (v2f){sA00.z, sA00.w},
                    (v2f){sA01.x, sA01.y}, (v2f){sA01.z, sA01.w}};
      v2f sv1[4] = {(v2f){sA10.x, sA10.y}, (v2f){sA10.z, sA10.w},
                    (v2f){sA11.x, sA11.y}, (v2f){sA11.z, sA11.w}};
      v2f hva[4] = {(v2f){hA00.x, hA00.y}, (v2f){hA00.z, hA00.w},
                    (v2f){hA01.x, hA01.y}, (v2f){hA01.z, hA01.w}};
      v2f hvb[4] = {(v2f){hA10.x, hA10.y}, (v2f){hA10.z, hA10.w},
                    (v2f){hA11.x, hA11.y}, (v2f){hA11.z, hA11.w}};
      v2f e00 = (v2f){rA0.z, rA0.z}, e01 = (v2f){rA0.w, rA0.w};
      v2f e10 = (v2f){rA1.z, rA1.z}, e11 = (v2f){rA1.w, rA1.w};
      v2f m0 = {0.f, 0.f}, m1 = {0.f, 0.f};
#pragma unroll
      for (int p = 0; p < 4; p++) {
        v2f hv0 = e00 * rwh0[p] + e01 * rwh1[p] + rbh[p];
        v2f gv0 = e00 * rwg0[p] + e01 * rwg1[p] + rbg[p];
        m0 += hva[p] * VMAX0(sv0[p] * hv0 + gv0);
        v2f hv1 = e10 * rwh0[p] + e11 * rwh1[p] + rbh[p];
        v2f gv1 = e10 * rwg0[p] + e11 * rwg1[p] + rbg[p];
        m1 += hvb[p] * VMAX0(sv1[p] * hv1 + gv1);
      }
      acc0 += m0.x + m0.y;
      acc1 += m1.x + m1.y;
    }
    // rotate pipeline
    rA0 = rB0; rA1 = rB1; rB0 = rC0; rB1 = rC1;
    hA00 = hB00; hA01 = hB01; hA10 = hB10; hA11 = hB11;
    sA00 = sB00; sA01 = sB01; sA10 = sB10; sA11 = sB11;
  }
  // odd tail edge
  if (degi & 1) {
    float4 r0 = es[end - 1];
    int s0 = __float_as_int(r0.x), t0 = __float_as_int(r0.y);
    const float4* hp0 = (const float4*)(h_in + s0 * 8);
    float4 a0 = hp0[0], a1 = hp0[1];
    const float4* ep0 = (const float4*)(embT + t0 * 512 + lane * 8);
    float4 s00 = ep0[0], s01 = ep0[1];
    v2f sv0[4] = {(v2f){s00.x, s00.y}, (v2f){s00.z, s00.w},
                  (v2f){s01.x, s01.y}, (v2f){s01.z, s01.w}};
    v2f hva[4] = {(v2f){a0.x, a0.y}, (v2f){a0.z, a0.w},
                  (v2f){a1.x, a1.y}, (v2f){a1.z, a1.w}};
    v2f e00 = (v2f){r0.z, r0.z}, e01 = (v2f){r0.w, r0.w};
    v2f m0 = {0.f, 0.f};
#pragma unroll
    for (int p = 0; p < 4; p++) {
      v2f hv0 = e00 * rwh0[p] + e01 * rwh1[p] + rbh[p];
      v2f gv0 = e00 * rwg0[p] + e01 * rwg1[p] + rbg[p];
      m0 += hva[p] * VMAX0(sv0[p] * hv0 + gv0);
    }
    acc0 += m0.x + m0.y;
  }
  float acc = acc0 + acc1;
  float deg = (float)degi;
  // epilogue: root/bias loaded here (not held during the loop)
  const float* hn = h_in + n * 8;
  float rt = bias[lane];
#pragma unroll
  for (int i = 0; i < 8; i++) rt = fmaf(hn[i], root[i * 64 + lane], rt);
  float val = fmaxf(rt + acc / fmaxf(deg, 1.f), 0.f);
  // fused gated pooling: batch = n / 1280 (contiguous batch layout)
  if (ct[n] == 1) {
    int b = n / (NN / NBATCH);
    unsafeAtomicAdd(&pooled[b * 64 + lane], val);
    if (lane == 0) unsafeAtomicAdd(&pcnt[b], 1.0f);
  }
}

// ---------------- pooling phase 2 + classifier + sigmoid (1 block) ----------
__global__ __launch_bounds__(1024) void pool2_kernel(
    const float* __restrict__ pooled, const float* __restrict__ pcnt,
    const float* __restrict__ clf_w, const float* __restrict__ clf_b,
    float* __restrict__ out) {
  int b = threadIdx.x >> 6, o = threadIdx.x & 63;
  float c = pcnt[b];
  float v = (pooled[b * 64 + o] / fmaxf(c, 1.f)) * clf_w[o];
#pragma unroll
  for (int d = 32; d; d >>= 1) v += __shfl_down(v, d);
  if (o == 0) out[b] = 1.f / (1.f + expf(-(v + clf_b[0])));
}

// ---------------------------------------------------------------------------
extern "C" void kernel_launch(void* const* d_in, const int* in_sizes, int n_in,
                              void* d_out, int out_size, void* d_ws, size_t ws_size,
                              hipStream_t stream) {
  (void)in_sizes; (void)n_in; (void)out_size; (void)ws_size;
  const float* x     = (const float*)d_in[0];
  const int*   eidx  = (const int*)d_in[1];
  const int*   src   = eidx;
  const int*   dst   = eidx + NE;
  const int*   etype = (const int*)d_in[2];
  const float* eattr = (const float*)d_in[3];
  const int*   ct    = (const int*)d_in[4];
  const float *emb[4], *wh[4], *bh[4], *wg[4], *bg[4], *root[4], *bias[4];
  for (int l = 0; l < 4; l++) {
    int b0 = 6 + 7 * l;
    emb[l]  = (const float*)d_in[b0 + 0];
    wh[l]   = (const float*)d_in[b0 + 1];
    bh[l]   = (const float*)d_in[b0 + 2];
    wg[l]   = (const float*)d_in[b0 + 3];
    bg[l]   = (const float*)d_in[b0 + 4];
    root[l] = (const float*)d_in[b0 + 5];
    bias[l] = (const float*)d_in[b0 + 6];
  }
  const float* clf_w = (const float*)d_in[34];
  const float* clf_b = (const float*)d_in[35];
  float* outp = (float*)d_out;

  // workspace layout (floats): ~11.96 MB (layout unchanged from R9)
  float* ws  = (float*)d_ws;
  int*    off    = (int*)ws;                      // NN+1 (pad 20484)
  float4* es     = (float4*)(ws + 20484);         // NE float4
  float*  hA     = ws + 20484 + 4 * NE;           // 8N
  float*  hB     = hA + 8 * NN;                   // 8N
  float*  h4     = hB + 8 * NN;                   // 64N (only cnt/cur alias used now)
  float*  embT4  = h4 + 64 * NN;                  // 36*512
  float*  pooled = embT4 + 36 * 512;              // 16*64
  float*  pcnt   = pooled + 16 * 64;              // 16
  int*    cnt    = (int*)h4;                      // alias
  int*    cur    = cnt + NN;                      // alias

  // ---- CSR build + embT4 transpose ----
  hipMemsetAsync(cnt, 0, NN * sizeof(int), stream);
  prep_kernel<<<NE / 256 + 72, 256, 0, stream>>>(dst, cnt, emb[3], embT4);
  scan_kernel<<<1, 1024, 0, stream>>>(cnt, off, cur, pooled);
  scatter_kernel<<<NE / 256, 256, 0, stream>>>(src, dst, etype, eattr, cur, es);

  // ---- 4 fused layers (l4 carries the gated pooling epilogue) ----
  layer_small16<<<2560, 256, 0, stream>>>(off, es, x,
      emb[0], wh[0], bh[0], wg[0], bg[0], root[0], bias[0], hA);
  layer_small8<<<1280, 256, 0, stream>>>(off, es, hA,
      emb[1], wh[1], bh[1], wg[1], bg[1], root[1], bias[1], hB);
  layer_small8<<<1280, 256, 0, stream>>>(off, es, hB,
      emb[2], wh[2], bh[2], wg[2], bg[2], root[2], bias[2], hA);
  layer_l4p<<<NN / 4, 256, 0, stream>>>(off, es, hA, embT4,
      wh[3], bh[3], wg[3], bg[3], root[3], bias[3], ct, pooled, pcnt);

  // ---- classifier + sigmoid ----
  pool2_kernel<<<1, 1024, 0, stream>>>(pooled, pcnt, clf_w, clf_b, outp);
}

// Round 11
// 295.690 us; speedup vs baseline: 1.3345x; 1.3345x over previous
//
#include <hip/hip_runtime.h>
#include <math.h>

#define NN 20480
#define NE 327680
#define NBATCH 16

typedef float v2f __attribute__((ext_vector_type(2)));

static __device__ __forceinline__ v2f vmax0(v2f a) {
  v2f r; r.x = fmaxf(a.x, 0.f); r.y = fmaxf(a.y, 0.f); return r;
}
#define VMAX0 vmax0

// ---------------- prep: histogram (1280 blk) + embT4 transpose (72 blk) -----
__global__ __launch_bounds__(256) void prep_kernel(
    const int* __restrict__ dst, int* __restrict__ cnt,
    const float* __restrict__ e4, float* __restrict__ t4) {
  int b = blockIdx.x;
  if (b < NE / 256) {
    int e = b * 256 + threadIdx.x;
    atomicAdd(&cnt[dst[e]], 1);
  } else {
    int idx = (b - NE / 256) * 256 + threadIdx.x;   // 0 .. 18431
    int t = idx >> 9, r = idx & 511, o = r >> 3, i = r & 7;
    t4[idx] = e4[(t << 9) + i * 64 + o];            // [t][i][o] -> [t][o][i]
  }
}

// ------- exclusive scan (1 block); writes off AND cur; zeroes pool ----------
__global__ __launch_bounds__(1024) void scan_kernel(const int* __restrict__ cnt,
                                                    int* __restrict__ off,
                                                    int* __restrict__ cur,
                                                    float* __restrict__ poolz) {
  __shared__ int part[1024];
  int tid = threadIdx.x;
  if (tid < NBATCH * 64 + NBATCH) poolz[tid] = 0.f;
  const int PT = NN / 1024;              // 20 per thread
  int loc[PT];
  int run = 0;
  int base = tid * PT;
#pragma unroll
  for (int k = 0; k < PT; k++) { loc[k] = run; run += cnt[base + k]; }
  part[tid] = run;
  __syncthreads();
  for (int d = 1; d < 1024; d <<= 1) {
    int t = (tid >= d) ? part[tid - d] : 0;
    __syncthreads();
    part[tid] += t;
    __syncthreads();
  }
  int pre = (tid == 0) ? 0 : part[tid - 1];
#pragma unroll
  for (int k = 0; k < PT; k++) {
    off[base + k] = pre + loc[k];
    cur[base + k] = pre + loc[k];
  }
  if (tid == 1023) off[NN] = pre + run;  // == NE
}

__global__ void scatter_kernel(const int* __restrict__ src, const int* __restrict__ dst,
                               const int* __restrict__ etype, const float* __restrict__ eattr,
                               int* __restrict__ cur, float4* __restrict__ es) {
  int e = blockIdx.x * blockDim.x + threadIdx.x;
  if (e >= NE) return;
  int d = dst[e];
  int pos = atomicAdd(&cur[d], 1);
  es[pos] = make_float4(__int_as_float(src[e]), __int_as_float(etype[e]),
                        eattr[2 * e], eattr[2 * e + 1]);
}

// ---------------- fused layer 1 (cin=16, cout=8) — unchanged (R9) -----------
__global__ __launch_bounds__(256) void layer_small16(
    const int* __restrict__ off, const float4* __restrict__ es,
    const float* __restrict__ h_in,
    const float* __restrict__ emb, const float* __restrict__ wh,
    const float* __restrict__ bh, const float* __restrict__ wg,
    const float* __restrict__ bg,
    const float* __restrict__ root, const float* __restrict__ bias,
    float* __restrict__ h_out) {
  constexpr int D = 128;
  constexpr int S = D + 1;               // odd stride spreads banks
  __shared__ float semb[36 * S];
  for (int idx = threadIdx.x; idx < 36 * D; idx += 256) {
    int t = idx / D, io = idx - t * D;
    semb[t * S + io] = emb[idx];
  }
  int lane = threadIdx.x & 63;
  int o = lane & 7;
  int ihalf = (lane >> 3) & 1;
  int esub = lane >> 4;                  // 0..3
  int ibase = ihalf * 8;
  v2f rwh0[4], rwh1[4], rbh[4], rwg0[4], rwg1[4], rbg[4], rroot[4];
#pragma unroll
  for (int p = 0; p < 4; p++) {
    int a = (ibase + 2 * p) * 8 + o, b = (ibase + 2 * p + 1) * 8 + o;
    rwh0[p] = (v2f){wh[a], wh[b]};
    rwh1[p] = (v2f){wh[D + a], wh[D + b]};
    rbh[p]  = (v2f){bh[a], bh[b]};
    rwg0[p] = (v2f){wg[a], wg[b]};
    rwg1[p] = (v2f){wg[D + a], wg[D + b]};
    rbg[p]  = (v2f){bg[a], bg[b]};
    rroot[p] = (v2f){root[a], root[b]};
  }
  float rbias = bias[o];
  __syncthreads();
  int wid = __builtin_amdgcn_readfirstlane(blockIdx.x * 4 + (threadIdx.x >> 6));
  for (int k = 0; k < 2; k++) {
    int n = wid * 2 + k;
    int beg = off[n], end = off[n + 1];
    float acc = 0.f;
    for (int j = beg + esub; j < end; j += 4) {
      float4 rec = es[j];
      int s = __float_as_int(rec.x);
      int t = __float_as_int(rec.y);
      v2f ef0 = (v2f){rec.z, rec.z}, ef1 = (v2f){rec.w, rec.w};
      const float4* hp = (const float4*)(h_in + s * 16 + ibase);
      float4 h0 = hp[0], h1 = hp[1];
      v2f hv[4] = {(v2f){h0.x, h0.y}, (v2f){h0.z, h0.w},
                   (v2f){h1.x, h1.y}, (v2f){h1.z, h1.w}};
      const float* st = &semb[t * S + ibase * 8 + o];
      v2f msg = {0.f, 0.f};
#pragma unroll
      for (int p = 0; p < 4; p++) {
        v2f hval = ef0 * rwh0[p] + ef1 * rwh1[p] + rbh[p];
        v2f gval = ef0 * rwg0[p] + ef1 * rwg1[p] + rbg[p];
        v2f stv = (v2f){st[(2 * p) * 8], st[(2 * p + 1) * 8]};
        msg += hv[p] * VMAX0(stv * hval + gval);
      }
      acc += msg.x + msg.y;
    }
    acc += __shfl_xor(acc, 8);
    acc += __shfl_xor(acc, 16);
    acc += __shfl_xor(acc, 32);
    const float* hn = h_in + n * 16 + ibase;
    v2f rtv = {0.f, 0.f};
#pragma unroll
    for (int p = 0; p < 4; p++)
      rtv += (v2f){hn[2 * p], hn[2 * p + 1]} * rroot[p];
    float rt = rtv.x + rtv.y;
    rt += __shfl_xor(rt, 8);
    float deg = (float)(end - beg);
    float val = fmaxf(rbias + rt + acc / fmaxf(deg, 1.f), 0.f);
    if (lane < 8) h_out[n * 8 + o] = val;
  }
}

// ---------------- fused layer, cin=8 cout=8 (L2,L3) — unchanged (R9) --------
__global__ __launch_bounds__(256) void layer_small8(
    const int* __restrict__ off, const float4* __restrict__ es,
    const float* __restrict__ h_in,
    const float* __restrict__ emb, const float* __restrict__ wh,
    const float* __restrict__ bh, const float* __restrict__ wg,
    const float* __restrict__ bg,
    const float* __restrict__ root, const float* __restrict__ bias,
    float* __restrict__ h_out) {
  constexpr int D = 64;
  constexpr int S = D + 1;
  __shared__ float semb[36 * S];
  for (int idx = threadIdx.x; idx < 36 * D; idx += 256) {
    int t = idx / D, io = idx - t * D;
    semb[t * S + io] = emb[idx];
  }
  int lane = threadIdx.x & 63;
  int o = lane & 7, esub = lane >> 3;
  v2f rwh0[4], rwh1[4], rbh[4], rwg0[4], rwg1[4], rbg[4], rroot[4];
#pragma unroll
  for (int p = 0; p < 4; p++) {
    int a = (2 * p) * 8 + o, b = (2 * p + 1) * 8 + o;
    rwh0[p] = (v2f){wh[a], wh[b]};
    rwh1[p] = (v2f){wh[D + a], wh[D + b]};
    rbh[p]  = (v2f){bh[a], bh[b]};
    rwg0[p] = (v2f){wg[a], wg[b]};
    rwg1[p] = (v2f){wg[D + a], wg[D + b]};
    rbg[p]  = (v2f){bg[a], bg[b]};
    rroot[p] = (v2f){root[a], root[b]};
  }
  float rbias = bias[o];
  __syncthreads();
  int wid = __builtin_amdgcn_readfirstlane(blockIdx.x * 4 + (threadIdx.x >> 6));
  for (int k = 0; k < 4; k++) {
    int n = wid * 4 + k;
    int beg = off[n], end = off[n + 1];
    float acc = 0.f;
    for (int j = beg + esub; j < end; j += 8) {
      float4 rec = es[j];
      int s = __float_as_int(rec.x);
      int t = __float_as_int(rec.y);
      v2f ef0 = (v2f){rec.z, rec.z}, ef1 = (v2f){rec.w, rec.w};
      const float4* hp = (const float4*)(h_in + s * 8);
      float4 h0 = hp[0], h1 = hp[1];
      v2f hv[4] = {(v2f){h0.x, h0.y}, (v2f){h0.z, h0.w},
                   (v2f){h1.x, h1.y}, (v2f){h1.z, h1.w}};
      const float* st = &semb[t * S + o];
      v2f msg = {0.f, 0.f};
#pragma unroll
      for (int p = 0; p < 4; p++) {
        v2f hval = ef0 * rwh0[p] + ef1 * rwh1[p] + rbh[p];
        v2f gval = ef0 * rwg0[p] + ef1 * rwg1[p] + rbg[p];
        v2f stv = (v2f){st[(2 * p) * 8], st[(2 * p + 1) * 8]};
        msg += hv[p] * VMAX0(stv * hval + gval);
      }
      acc += msg.x + msg.y;
    }
    acc += __shfl_xor(acc, 8);
    acc += __shfl_xor(acc, 16);
    acc += __shfl_xor(acc, 32);
    float deg = (float)(end - beg);
    const float* hn = h_in + n * 8;
    v2f rtv = {0.f, 0.f};
#pragma unroll
    for (int p = 0; p < 4; p++)
      rtv += (v2f){hn[2 * p], hn[2 * p + 1]} * rroot[p];
    float val = fmaxf(rbias + rtv.x + rtv.y + acc / fmaxf(deg, 1.f), 0.f);
    if (lane < 8) h_out[n * 8 + o] = val;
  }
}

// ---------------- fused layer 4 (cin=8, cout=64) — LDS-staged edges ---------
// Block = 4 waves = 4 consecutive nodes; their edge records are CONTIGUOUS in
// es. Stage the slab into LDS with coalesced per-lane float4 loads (deep
// vmcnt queue), then the K-loop reads recs from LDS (same-address broadcast)
// and h/emb via per-lane VECTOR loads — no scalar-cache miss chain at all.
__global__ __launch_bounds__(256) void layer_l4s(
    const int* __restrict__ off, const float4* __restrict__ es,
    const float* __restrict__ h_in, const float* __restrict__ embT,
    const float* __restrict__ wh, const float* __restrict__ bh,
    const float* __restrict__ wg, const float* __restrict__ bg,
    const float* __restrict__ root, const float* __restrict__ bias,
    float* __restrict__ h_out) {
  __shared__ float4 sedge[256];              // 4KB; slab mean=64, cap 256
  int tid = threadIdx.x;
  int lane = tid & 63;
  v2f rwh0[4], rwh1[4], rbh[4], rwg0[4], rwg1[4], rbg[4], rroot[4];
#pragma unroll
  for (int p = 0; p < 4; p++) {
    int a = (2 * p) * 64 + lane, b = (2 * p + 1) * 64 + lane;
    rwh0[p] = (v2f){wh[a], wh[b]};
    rwh1[p] = (v2f){wh[512 + a], wh[512 + b]};
    rbh[p]  = (v2f){bh[a], bh[b]};
    rwg0[p] = (v2f){wg[a], wg[b]};
    rwg1[p] = (v2f){wg[512 + a], wg[512 + b]};
    rbg[p]  = (v2f){bg[a], bg[b]};
    rroot[p] = (v2f){root[a], root[b]};
  }
  float rbias = bias[lane];
  int n0 = blockIdx.x * 4;
  int sBeg = off[n0];
  int slab = off[n0 + 4] - sBeg;
  for (int i = tid; i < slab && i < 256; i += 256) sedge[i] = es[sBeg + i];
  __syncthreads();
  int n = __builtin_amdgcn_readfirstlane(n0 + (tid >> 6));
  int beg = off[n], end = off[n + 1];
  int degi = end - beg;
  float acc0 = 0.f, acc1 = 0.f;

  auto edge_msg2 = [&](float4 r0, float4 r1) {
    int s0 = __float_as_int(r0.x), t0 = __float_as_int(r0.y);
    int s1 = __float_as_int(r1.x), t1 = __float_as_int(r1.y);
    const float4* hp0 = (const float4*)(h_in + s0 * 8);   // vector loads
    const float4* hp1 = (const float4*)(h_in + s1 * 8);
    float4 a0 = hp0[0], a1 = hp0[1];
    float4 b0 = hp1[0], b1 = hp1[1];
    const float4* ep0 = (const float4*)(embT + t0 * 512 + lane * 8);
    const float4* ep1 = (const float4*)(embT + t1 * 512 + lane * 8);
    float4 s00 = ep0[0], s01 = ep0[1];
    float4 s10 = ep1[0], s11 = ep1[1];
    v2f sv0[4] = {(v2f){s00.x, s00.y}, (v2f){s00.z, s00.w},
                  (v2f){s01.x, s01.y}, (v2f){s01.z, s01.w}};
    v2f sv1[4] = {(v2f){s10.x, s10.y}, (v2f){s10.z, s10.w},
                  (v2f){s11.x, s11.y}, (v2f){s11.z, s11.w}};
    v2f hva[4] = {(v2f){a0.x, a0.y}, (v2f){a0.z, a0.w},
                  (v2f){a1.x, a1.y}, (v2f){a1.z, a1.w}};
    v2f hvb[4] = {(v2f){b0.x, b0.y}, (v2f){b0.z, b0.w},
                  (v2f){b1.x, b1.y}, (v2f){b1.z, b1.w}};
    v2f e00 = (v2f){r0.z, r0.z}, e01 = (v2f){r0.w, r0.w};
    v2f e10 = (v2f){r1.z, r1.z}, e11 = (v2f){r1.w, r1.w};
    v2f m0 = {0.f, 0.f}, m1 = {0.f, 0.f};
#pragma unroll
    for (int p = 0; p < 4; p++) {
      v2f hv0 = e00 * rwh0[p] + e01 * rwh1[p] + rbh[p];
      v2f gv0 = e00 * rwg0[p] + e01 * rwg1[p] + rbg[p];
      m0 += hva[p] * VMAX0(sv0[p] * hv0 + gv0);
      v2f hv1 = e10 * rwh0[p] + e11 * rwh1[p] + rbh[p];
      v2f gv1 = e10 * rwg0[p] + e11 * rwg1[p] + rbg[p];
      m1 += hvb[p] * VMAX0(sv1[p] * hv1 + gv1);
    }
    acc0 += m0.x + m0.y;
    acc1 += m1.x + m1.y;
  };
  auto edge_msg1 = [&](float4 r0) {
    int s0 = __float_as_int(r0.x), t0 = __float_as_int(r0.y);
    const float4* hp0 = (const float4*)(h_in + s0 * 8);
    float4 a0 = hp0[0], a1 = hp0[1];
    const float4* ep0 = (const float4*)(embT + t0 * 512 + lane * 8);
    float4 s00 = ep0[0], s01 = ep0[1];
    v2f sv0[4] = {(v2f){s00.x, s00.y}, (v2f){s00.z, s00.w},
                  (v2f){s01.x, s01.y}, (v2f){s01.z, s01.w}};
    v2f hva[4] = {(v2f){a0.x, a0.y}, (v2f){a0.z, a0.w},
                  (v2f){a1.x, a1.y}, (v2f){a1.z, a1.w}};
    v2f e00 = (v2f){r0.z, r0.z}, e01 = (v2f){r0.w, r0.w};
    v2f m0 = {0.f, 0.f};
#pragma unroll
    for (int p = 0; p < 4; p++) {
      v2f hv0 = e00 * rwh0[p] + e01 * rwh1[p] + rbh[p];
      v2f gv0 = e00 * rwg0[p] + e01 * rwg1[p] + rbg[p];
      m0 += hva[p] * VMAX0(sv0[p] * hv0 + gv0);
    }
    acc0 += m0.x + m0.y;
  };

  if (slab <= 256) {                       // fast path (essentially always)
    int i = beg - sBeg;
    int iend = i + degi;
    for (; i + 2 <= iend; i += 2) edge_msg2(sedge[i], sedge[i + 1]);
    if (i < iend) edge_msg1(sedge[i]);
  } else {                                 // safety fallback: direct vector loads
    int e = beg;
    for (; e + 2 <= end; e += 2) edge_msg2(es[e], es[e + 1]);
    if (e < end) edge_msg1(es[e]);
  }
  float acc = acc0 + acc1;
  float deg = (float)degi;
  const float* hn = h_in + n * 8;
  v2f rtv = {0.f, 0.f};
#pragma unroll
  for (int p = 0; p < 4; p++)
    rtv += (v2f){hn[2 * p], hn[2 * p + 1]} * rroot[p];
  h_out[n * 64 + lane] = fmaxf(rbias + rtv.x + rtv.y + acc / fmaxf(deg, 1.f), 0.f);
}

// ---------------- gated pooling, phase 1: 320 blocks ------------------------
__global__ __launch_bounds__(256) void pool1_kernel(
    const float* __restrict__ h4, const int* __restrict__ ct,
    float* __restrict__ pooled, float* __restrict__ pcnt) {
  __shared__ float ss[4][64];
  __shared__ float sc[4];
  int b = blockIdx.x / 20, c = blockIdx.x % 20;
  int base = b * (NN / NBATCH) + c * 64;
  int o = threadIdx.x & 63, sub = threadIdx.x >> 6;
  float sum = 0.f, cnt = 0.f;
  for (int j = sub; j < 64; j += 4) {
    int n = base + j;
    if (ct[n] == 1) { sum += h4[n * 64 + o]; cnt += 1.f; }
  }
  ss[sub][o] = sum;
  if (o == 0) sc[sub] = cnt;
  __syncthreads();
  if (threadIdx.x < 64) {
    float tot = ss[0][o] + ss[1][o] + ss[2][o] + ss[3][o];
    unsafeAtomicAdd(&pooled[b * 64 + o], tot);
    if (o == 0) unsafeAtomicAdd(&pcnt[b], sc[0] + sc[1] + sc[2] + sc[3]);
  }
}

// ---------------- pooling phase 2 + classifier + sigmoid (1 block) ----------
__global__ __launch_bounds__(1024) void pool2_kernel(
    const float* __restrict__ pooled, const float* __restrict__ pcnt,
    const float* __restrict__ clf_w, const float* __restrict__ clf_b,
    float* __restrict__ out) {
  int b = threadIdx.x >> 6, o = threadIdx.x & 63;
  float c = pcnt[b];
  float v = (pooled[b * 64 + o] / fmaxf(c, 1.f)) * clf_w[o];
#pragma unroll
  for (int d = 32; d; d >>= 1) v += __shfl_down(v, d);
  if (o == 0) out[b] = 1.f / (1.f + expf(-(v + clf_b[0])));
}

// ---------------------------------------------------------------------------
extern "C" void kernel_launch(void* const* d_in, const int* in_sizes, int n_in,
                              void* d_out, int out_size, void* d_ws, size_t ws_size,
                              hipStream_t stream) {
  (void)in_sizes; (void)n_in; (void)out_size; (void)ws_size;
  const float* x     = (const float*)d_in[0];
  const int*   eidx  = (const int*)d_in[1];
  const int*   src   = eidx;
  const int*   dst   = eidx + NE;
  const int*   etype = (const int*)d_in[2];
  const float* eattr = (const float*)d_in[3];
  const int*   ct    = (const int*)d_in[4];
  const float *emb[4], *wh[4], *bh[4], *wg[4], *bg[4], *root[4], *bias[4];
  for (int l = 0; l < 4; l++) {
    int b0 = 6 + 7 * l;
    emb[l]  = (const float*)d_in[b0 + 0];
    wh[l]   = (const float*)d_in[b0 + 1];
    bh[l]   = (const float*)d_in[b0 + 2];
    wg[l]   = (const float*)d_in[b0 + 3];
    bg[l]   = (const float*)d_in[b0 + 4];
    root[l] = (const float*)d_in[b0 + 5];
    bias[l] = (const float*)d_in[b0 + 6];
  }
  const float* clf_w = (const float*)d_in[34];
  const float* clf_b = (const float*)d_in[35];
  float* outp = (float*)d_out;

  // workspace layout (floats): ~11.96 MB (unchanged from R9)
  float* ws  = (float*)d_ws;
  int*    off    = (int*)ws;                      // NN+1 (pad 20484)
  float4* es     = (float4*)(ws + 20484);         // NE float4
  float*  hA     = ws + 20484 + 4 * NE;           // 8N
  float*  hB     = hA + 8 * NN;                   // 8N
  float*  h4     = hB + 8 * NN;                   // 64N
  float*  embT4  = h4 + 64 * NN;                  // 36*512
  float*  pooled = embT4 + 36 * 512;              // 16*64
  float*  pcnt   = pooled + 16 * 64;              // 16
  int*    cnt    = (int*)h4;                      // alias (dead until L4)
  int*    cur    = cnt + NN;                      // alias

  // ---- CSR build + embT4 transpose ----
  hipMemsetAsync(cnt, 0, NN * sizeof(int), stream);
  prep_kernel<<<NE / 256 + 72, 256, 0, stream>>>(dst, cnt, emb[3], embT4);
  scan_kernel<<<1, 1024, 0, stream>>>(cnt, off, cur, pooled);
  scatter_kernel<<<NE / 256, 256, 0, stream>>>(src, dst, etype, eattr, cur, es);

  // ---- 4 fused layers ----
  layer_small16<<<2560, 256, 0, stream>>>(off, es, x,
      emb[0], wh[0], bh[0], wg[0], bg[0], root[0], bias[0], hA);
  layer_small8<<<1280, 256, 0, stream>>>(off, es, hA,
      emb[1], wh[1], bh[1], wg[1], bg[1], root[1], bias[1], hB);
  layer_small8<<<1280, 256, 0, stream>>>(off, es, hB,
      emb[2], wh[2], bh[2], wg[2], bg[2], root[2], bias[2], hA);
  layer_l4s<<<NN / 4, 256, 0, stream>>>(off, es, hA, embT4,
      wh[3], bh[3], wg[3], bg[3], root[3], bias[3], h4);

  // ---- pooling + classifier + sigmoid ----
  pool1_kernel<<<320, 256, 0, stream>>>(h4, ct, pooled, pcnt);
  pool2_kernel<<<1, 1024, 0, stream>>>(pooled, pcnt, clf_w, clf_b, outp);
}